// Round 1
// baseline (2874.160 us; speedup 1.0000x reference)
//
#include <hip/hip_runtime.h>
#include <hip/hip_bf16.h>

#define N_NODES 50000
#define N_EDGES 800000
#define D 128

// ---------------- degree / normalization ----------------

__global__ void deg_init_kernel(float* __restrict__ deg) {
    int n = blockIdx.x * blockDim.x + threadIdx.x;
    if (n < N_NODES) deg[n] = 1.0f;   // self-loop contributes 1
}

__global__ void deg_count_kernel(const int* __restrict__ dst, float* __restrict__ deg) {
    int e = blockIdx.x * blockDim.x + threadIdx.x;
    if (e < N_EDGES) atomicAdd(&deg[dst[e]], 1.0f);
}

__global__ void dinv_kernel(const float* __restrict__ deg, float* __restrict__ dinv) {
    int n = blockIdx.x * blockDim.x + threadIdx.x;
    if (n < N_NODES) dinv[n] = rsqrtf(deg[n]);
}

// ---------------- f32 GEMM: C[M,128] = A[M,128] @ W[128,128] ----------------
// 32-row tile per block, 256 threads, 4x4 register blocking, K-tiled by 32.
template<bool RELU>
__global__ __launch_bounds__(256) void gemm128_kernel(const float* __restrict__ A,
                                                      const float* __restrict__ W,
                                                      float* __restrict__ C, int M) {
    __shared__ float ws[32][128];   // W k-tile
    __shared__ float xs[32][36];    // A tile, padded stride 36 (16B-aligned rows)
    const int tid = threadIdx.x;
    const int tx = tid & 31;   // col group -> cols tx*4..tx*4+3
    const int ty = tid >> 5;   // 0..7      -> rows ty*4..ty*4+3
    const int row0 = blockIdx.x * 32;

    float acc[4][4] = {};

    for (int kt = 0; kt < 128; kt += 32) {
        // load W tile: rows kt..kt+31 x 128 cols (1024 float4, 4 per thread)
        #pragma unroll
        for (int i = 0; i < 4; ++i) {
            int idx = tid + i * 256;       // 0..1023
            int r = idx >> 5;              // 0..31
            int c4 = idx & 31;             // 0..31
            *(float4*)&ws[r][c4 * 4] = *(const float4*)&W[(kt + r) * D + c4 * 4];
        }
        // load A tile: 32 rows x 32 cols (1 float4 per thread)
        {
            int r = tid >> 3;              // 0..31
            int c4 = tid & 7;              // 0..7
            int grow = row0 + r;
            float4 v = {0.f, 0.f, 0.f, 0.f};
            if (grow < M) v = *(const float4*)&A[grow * D + kt + c4 * 4];
            if (RELU) {
                v.x = fmaxf(v.x, 0.f); v.y = fmaxf(v.y, 0.f);
                v.z = fmaxf(v.z, 0.f); v.w = fmaxf(v.w, 0.f);
            }
            *(float4*)&xs[r][c4 * 4] = v;
        }
        __syncthreads();
        #pragma unroll
        for (int k = 0; k < 32; ++k) {
            float4 wv = *(float4*)&ws[k][tx * 4];
            float xv[4];
            #pragma unroll
            for (int i = 0; i < 4; ++i) xv[i] = xs[ty * 4 + i][k];
            #pragma unroll
            for (int i = 0; i < 4; ++i) {
                acc[i][0] += xv[i] * wv.x;
                acc[i][1] += xv[i] * wv.y;
                acc[i][2] += xv[i] * wv.z;
                acc[i][3] += xv[i] * wv.w;
            }
        }
        __syncthreads();
    }
    #pragma unroll
    for (int i = 0; i < 4; ++i) {
        int grow = row0 + ty * 4 + i;
        if (grow < M) {
            float4 v = {acc[i][0], acc[i][1], acc[i][2], acc[i][3]};
            *(float4*)&C[grow * D + tx * 4] = v;
        }
    }
}

// ---------------- aggregation ----------------
// out[n][:] = h[n][:] * dinv[n]^2 + bias[:]   (self-loop + bias folded in; WRITES, no read)
__global__ void agg_init_kernel(const float* __restrict__ h, const float* __restrict__ dinv,
                                const float* __restrict__ bias, float* __restrict__ out) {
    int gid = blockIdx.x * blockDim.x + threadIdx.x;   // N_NODES*32 threads
    if (gid >= N_NODES * 32) return;
    int n = gid >> 5;
    int l = gid & 31;
    float dn = dinv[n];
    float s = dn * dn;
    float4 hv = *(const float4*)&h[n * D + l * 4];
    float4 bv = *(const float4*)&bias[l * 4];
    float4 o = {hv.x * s + bv.x, hv.y * s + bv.y, hv.z * s + bv.z, hv.w * s + bv.w};
    *(float4*)&out[n * D + l * 4] = o;
}

// per edge: out[dst][:] += h[src][:] * dinv[src]*dinv[dst]   (32 lanes/edge, 4 floats/lane)
__global__ void agg_edges_kernel(const float* __restrict__ h, const float* __restrict__ dinv,
                                 const int* __restrict__ src, const int* __restrict__ dst,
                                 float* __restrict__ out) {
    long long gid = (long long)blockIdx.x * blockDim.x + threadIdx.x;
    int e = (int)(gid >> 5);
    int l = (int)(gid & 31);
    if (e >= N_EDGES) return;
    int s = src[e];
    int d = dst[e];
    float norm = dinv[s] * dinv[d];
    float4 hv = *(const float4*)&h[s * D + l * 4];
    float* op = &out[d * D + l * 4];
    atomicAdd(op + 0, hv.x * norm);
    atomicAdd(op + 1, hv.y * norm);
    atomicAdd(op + 2, hv.z * norm);
    atomicAdd(op + 3, hv.w * norm);
}

extern "C" void kernel_launch(void* const* d_in, const int* in_sizes, int n_in,
                              void* d_out, int out_size, void* d_ws, size_t ws_size,
                              hipStream_t stream) {
    const float* x  = (const float*)d_in[0];
    const int*   ei = (const int*)d_in[1];     // [2, N_EDGES] row-major, int32
    const float* W1 = (const float*)d_in[2];
    const float* b1 = (const float*)d_in[3];
    const float* W2 = (const float*)d_in[4];
    const float* b2 = (const float*)d_in[5];
    float* out = (float*)d_out;

    const int* src = ei;
    const int* dst = ei + N_EDGES;

    float* ws   = (float*)d_ws;
    float* deg  = ws;                       // [N]
    float* dinv = ws + 50176;               // [N]
    float* h    = ws + 100352;              // [N,128]  (reused as g for layer 2)
    float* agg1 = h + (size_t)N_NODES * D;  // [N,128]
    // total ws: (100352 + 2*6,400,000)*4 B ~= 51.6 MB

    const int B = 256;
    dim3 blk(B);

    deg_init_kernel<<<(N_NODES + B - 1) / B, blk, 0, stream>>>(deg);
    deg_count_kernel<<<(N_EDGES + B - 1) / B, blk, 0, stream>>>(dst, deg);
    dinv_kernel<<<(N_NODES + B - 1) / B, blk, 0, stream>>>(deg, dinv);

    int gemm_grid = (N_NODES + 31) / 32;
    // layer 1: h = x @ W1
    gemm128_kernel<false><<<gemm_grid, blk, 0, stream>>>(x, W1, h, N_NODES);
    // agg1 = selfloop + b1, then edge scatter
    agg_init_kernel<<<(N_NODES * 32 + B - 1) / B, blk, 0, stream>>>(h, dinv, b1, agg1);
    agg_edges_kernel<<<(int)(((long long)N_EDGES * 32 + B - 1) / B), blk, 0, stream>>>(
        h, dinv, src, dst, agg1);

    // layer 2: g = relu(agg1) @ W2  (g reuses h buffer)
    gemm128_kernel<true><<<gemm_grid, blk, 0, stream>>>(agg1, W2, h, N_NODES);
    agg_init_kernel<<<(N_NODES * 32 + B - 1) / B, blk, 0, stream>>>(h, dinv, b2, out);
    agg_edges_kernel<<<(int)(((long long)N_EDGES * 32 + B - 1) / B), blk, 0, stream>>>(
        h, dinv, src, dst, out);
}

// Round 2
// 438.198 us; speedup vs baseline: 6.5590x; 6.5590x over previous
//
#include <hip/hip_runtime.h>
#include <hip/hip_bf16.h>

#define N_NODES 50000
#define N_EDGES 800000
#define D 128

// ---------------- degree counting ----------------

__global__ void cnt_init_kernel(int* __restrict__ cnt) {
    int n = blockIdx.x * blockDim.x + threadIdx.x;
    if (n < N_NODES) cnt[n] = 0;
}

__global__ void deg_count_kernel(const int* __restrict__ dst, int* __restrict__ cnt) {
    int e = blockIdx.x * blockDim.x + threadIdx.x;
    if (e < N_EDGES) atomicAdd(&cnt[dst[e]], 1);
}

__global__ void dinv_kernel(const int* __restrict__ cnt, float* __restrict__ dinv) {
    int n = blockIdx.x * blockDim.x + threadIdx.x;
    if (n < N_NODES) dinv[n] = rsqrtf((float)cnt[n] + 1.0f);  // +1 = self-loop
}

// ---------------- exclusive scan (single block, 1024 threads) ----------------

__global__ __launch_bounds__(1024) void scan_kernel(const int* __restrict__ cnt,
                                                    int* __restrict__ offs,
                                                    int* __restrict__ cursor) {
    __shared__ int sums[1024];
    const int t = threadIdx.x;
    const int CH = (N_NODES + 1023) / 1024;   // 49
    int b = t * CH;
    int e = min(b + CH, N_NODES);
    int s = 0;
    for (int i = b; i < e; ++i) s += cnt[i];
    sums[t] = s;
    __syncthreads();
    // inclusive Hillis-Steele scan
    for (int off = 1; off < 1024; off <<= 1) {
        int add = (t >= off) ? sums[t - off] : 0;
        __syncthreads();
        sums[t] += add;
        __syncthreads();
    }
    int run = sums[t] - s;   // exclusive prefix for this chunk
    for (int i = b; i < e; ++i) {
        offs[i] = run;
        cursor[i] = run;
        run += cnt[i];
    }
}

__global__ void scatter_kernel(const int* __restrict__ src, const int* __restrict__ dst,
                               int* __restrict__ cursor, int* __restrict__ csr) {
    int e = blockIdx.x * blockDim.x + threadIdx.x;
    if (e < N_EDGES) {
        int pos = atomicAdd(&cursor[dst[e]], 1);
        csr[pos] = src[e];
    }
}

// ---------------- f32 GEMM: C[M,128] = (relu?)A[M,128] @ W[128,128], *dinv[row] ----------
template<bool RELU>
__global__ __launch_bounds__(256) void gemm128_kernel(const float* __restrict__ A,
                                                      const float* __restrict__ W,
                                                      const float* __restrict__ dinv,
                                                      float* __restrict__ C, int M) {
    __shared__ float ws[32][128];   // W k-tile
    __shared__ float xs[32][36];    // A tile, padded
    const int tid = threadIdx.x;
    const int tx = tid & 31;   // cols tx*4..tx*4+3
    const int ty = tid >> 5;   // rows ty*4..ty*4+3
    const int row0 = blockIdx.x * 32;

    float acc[4][4] = {};

    for (int kt = 0; kt < 128; kt += 32) {
        #pragma unroll
        for (int i = 0; i < 4; ++i) {
            int idx = tid + i * 256;
            int r = idx >> 5;
            int c4 = idx & 31;
            *(float4*)&ws[r][c4 * 4] = *(const float4*)&W[(kt + r) * D + c4 * 4];
        }
        {
            int r = tid >> 3;
            int c4 = tid & 7;
            int grow = row0 + r;
            float4 v = {0.f, 0.f, 0.f, 0.f};
            if (grow < M) v = *(const float4*)&A[grow * D + kt + c4 * 4];
            if (RELU) {
                v.x = fmaxf(v.x, 0.f); v.y = fmaxf(v.y, 0.f);
                v.z = fmaxf(v.z, 0.f); v.w = fmaxf(v.w, 0.f);
            }
            *(float4*)&xs[r][c4 * 4] = v;
        }
        __syncthreads();
        #pragma unroll
        for (int k = 0; k < 32; ++k) {
            float4 wv = *(float4*)&ws[k][tx * 4];
            float xv[4];
            #pragma unroll
            for (int i = 0; i < 4; ++i) xv[i] = xs[ty * 4 + i][k];
            #pragma unroll
            for (int i = 0; i < 4; ++i) {
                acc[i][0] += xv[i] * wv.x;
                acc[i][1] += xv[i] * wv.y;
                acc[i][2] += xv[i] * wv.z;
                acc[i][3] += xv[i] * wv.w;
            }
        }
        __syncthreads();
    }
    #pragma unroll
    for (int i = 0; i < 4; ++i) {
        int grow = row0 + ty * 4 + i;
        if (grow < M) {
            float dn = dinv[grow];
            float4 v = {acc[i][0] * dn, acc[i][1] * dn, acc[i][2] * dn, acc[i][3] * dn};
            *(float4*)&C[grow * D + tx * 4] = v;
        }
    }
}

// ---------------- CSR gather-aggregate ----------------
// out[n][:] = dinv[n] * ( sum_{s in in(n)} hn[s][:] + hn[n][:] ) + bias[:]
// hn is already scaled by dinv[src] (GEMM epilogue). One wave per node, float2/lane.
__global__ __launch_bounds__(256) void gather_kernel(const float* __restrict__ hn,
                                                     const float* __restrict__ dinv,
                                                     const int* __restrict__ offs,
                                                     const int* __restrict__ cnt,
                                                     const int* __restrict__ csr,
                                                     const float* __restrict__ bias,
                                                     float* __restrict__ out) {
    const int wid = threadIdx.x >> 6;       // wave in block: 0..3
    const int lane = threadIdx.x & 63;
    const int n = blockIdx.x * 4 + wid;
    if (n >= N_NODES) return;
    const int beg = offs[n];
    const int m = cnt[n];
    const int col = lane * 2;

    float ax = 0.f, ay = 0.f;
    int i = 0;
    for (; i + 4 <= m; i += 4) {
        int s0 = csr[beg + i];
        int s1 = csr[beg + i + 1];
        int s2 = csr[beg + i + 2];
        int s3 = csr[beg + i + 3];
        float2 v0 = *(const float2*)&hn[(size_t)s0 * D + col];
        float2 v1 = *(const float2*)&hn[(size_t)s1 * D + col];
        float2 v2 = *(const float2*)&hn[(size_t)s2 * D + col];
        float2 v3 = *(const float2*)&hn[(size_t)s3 * D + col];
        ax += v0.x + v1.x + v2.x + v3.x;
        ay += v0.y + v1.y + v2.y + v3.y;
    }
    for (; i < m; ++i) {
        int s = csr[beg + i];
        float2 v = *(const float2*)&hn[(size_t)s * D + col];
        ax += v.x;
        ay += v.y;
    }
    float dn = dinv[n];
    float2 hv = *(const float2*)&hn[(size_t)n * D + col];
    float2 bv = *(const float2*)&bias[col];
    float2 o = { dn * (ax + hv.x) + bv.x, dn * (ay + hv.y) + bv.y };
    *(float2*)&out[(size_t)n * D + col] = o;
}

extern "C" void kernel_launch(void* const* d_in, const int* in_sizes, int n_in,
                              void* d_out, int out_size, void* d_ws, size_t ws_size,
                              hipStream_t stream) {
    const float* x  = (const float*)d_in[0];
    const int*   ei = (const int*)d_in[1];     // [2, N_EDGES], int32 on device
    const float* W1 = (const float*)d_in[2];
    const float* b1 = (const float*)d_in[3];
    const float* W2 = (const float*)d_in[4];
    const float* b2 = (const float*)d_in[5];
    float* out = (float*)d_out;

    const int* src = ei;
    const int* dst = ei + N_EDGES;

    // workspace layout (4-byte units)
    char* wsb = (char*)d_ws;
    int*   cnt    = (int*)(wsb);                                 // [50176]
    int*   cursor = cnt + 50176;                                 // [50176]
    int*   offs   = cursor + 50176;                              // [50176]
    float* dinv   = (float*)(offs + 50176);                      // [50176]
    int*   csr    = (int*)(dinv + 50176);                        // [800000]
    float* hn     = (float*)(csr + 800000);                      // [N,128]
    float* agg1   = hn + (size_t)N_NODES * D;                    // [N,128]
    // total ~= 55.2 MB

    const int B = 256;

    cnt_init_kernel<<<(N_NODES + B - 1) / B, B, 0, stream>>>(cnt);
    deg_count_kernel<<<(N_EDGES + B - 1) / B, B, 0, stream>>>(dst, cnt);
    dinv_kernel<<<(N_NODES + B - 1) / B, B, 0, stream>>>(cnt, dinv);
    scan_kernel<<<1, 1024, 0, stream>>>(cnt, offs, cursor);
    scatter_kernel<<<(N_EDGES + B - 1) / B, B, 0, stream>>>(src, dst, cursor, csr);

    const int gemm_grid = (N_NODES + 31) / 32;
    const int gather_grid = (N_NODES + 3) / 4;

    // layer 1: hn = (x @ W1) * dinv[row]
    gemm128_kernel<false><<<gemm_grid, B, 0, stream>>>(x, W1, dinv, hn, N_NODES);
    gather_kernel<<<gather_grid, B, 0, stream>>>(hn, dinv, offs, cnt, csr, b1, agg1);

    // layer 2: hn2 = (relu(agg1) @ W2) * dinv[row]   (reuses hn buffer)
    gemm128_kernel<true><<<gemm_grid, B, 0, stream>>>(agg1, W2, dinv, hn, N_NODES);
    gather_kernel<<<gather_grid, B, 0, stream>>>(hn, dinv, offs, cnt, csr, b2, out);
}

// Round 3
// 339.256 us; speedup vs baseline: 8.4720x; 1.2916x over previous
//
#include <hip/hip_runtime.h>
#include <hip/hip_bf16.h>

#define N_NODES 50000
#define N_EDGES 800000
#define D 128
#define NBLK 196   // ceil(50000/256)

// ---------------- degree counting ----------------

__global__ void cnt_init_kernel(int* __restrict__ cnt) {
    int n = blockIdx.x * blockDim.x + threadIdx.x;
    if (n < N_NODES) cnt[n] = 0;
}

__global__ void deg_count_kernel(const int* __restrict__ dst, int* __restrict__ cnt) {
    int e = blockIdx.x * blockDim.x + threadIdx.x;
    if (e < N_EDGES) atomicAdd(&cnt[dst[e]], 1);
}

// ---------------- hierarchical exclusive scan ----------------

// phase 1: per-block sums of cnt (256 nodes per block)
__global__ __launch_bounds__(256) void blocksum_kernel(const int* __restrict__ cnt,
                                                       int* __restrict__ partial) {
    __shared__ int red[256];
    const int t = threadIdx.x;
    int i = blockIdx.x * 256 + t;
    red[t] = (i < N_NODES) ? cnt[i] : 0;
    __syncthreads();
    #pragma unroll
    for (int off = 128; off > 0; off >>= 1) {
        if (t < off) red[t] += red[t + off];
        __syncthreads();
    }
    if (t == 0) partial[blockIdx.x] = red[0];
}

// phase 2: exclusive scan of NBLK partials (single block)
__global__ __launch_bounds__(256) void scan_partials_kernel(int* __restrict__ partial) {
    __shared__ int s[256];
    const int t = threadIdx.x;
    int v = (t < NBLK) ? partial[t] : 0;
    s[t] = v;
    __syncthreads();
    #pragma unroll
    for (int off = 1; off < 256; off <<= 1) {
        int add = (t >= off) ? s[t - off] : 0;
        __syncthreads();
        s[t] += add;
        __syncthreads();
    }
    if (t < NBLK) partial[t] = s[t] - v;   // exclusive
}

// phase 3: per-block exclusive scan + block offset; writes offs, cursor, dinv
__global__ __launch_bounds__(256) void scan_block_kernel(const int* __restrict__ cnt,
                                                         const int* __restrict__ partial,
                                                         int* __restrict__ offs,
                                                         int* __restrict__ cursor,
                                                         float* __restrict__ dinv) {
    __shared__ int s[256];
    const int t = threadIdx.x;
    int i = blockIdx.x * 256 + t;
    int v = (i < N_NODES) ? cnt[i] : 0;
    s[t] = v;
    __syncthreads();
    #pragma unroll
    for (int off = 1; off < 256; off <<= 1) {
        int add = (t >= off) ? s[t - off] : 0;
        __syncthreads();
        s[t] += add;
        __syncthreads();
    }
    if (i < N_NODES) {
        int o = s[t] - v + partial[blockIdx.x];
        offs[i] = o;
        cursor[i] = o;
        dinv[i] = rsqrtf((float)v + 1.0f);   // +1 = self-loop
    }
}

__global__ void scatter_kernel(const int* __restrict__ src, const int* __restrict__ dst,
                               int* __restrict__ cursor, int* __restrict__ csr) {
    int e = blockIdx.x * blockDim.x + threadIdx.x;
    if (e < N_EDGES) {
        int pos = atomicAdd(&cursor[dst[e]], 1);
        csr[pos] = src[e];
    }
}

// ---------------- f32 GEMM: C[M,128] = (relu?)A[M,128] @ W[128,128], *dinv[row] ----------
template<bool RELU>
__global__ __launch_bounds__(256) void gemm128_kernel(const float* __restrict__ A,
                                                      const float* __restrict__ W,
                                                      const float* __restrict__ dinv,
                                                      float* __restrict__ C, int M) {
    __shared__ float ws[32][128];   // W k-tile
    __shared__ float xs[32][36];    // A tile, padded
    const int tid = threadIdx.x;
    const int tx = tid & 31;   // cols tx*4..tx*4+3
    const int ty = tid >> 5;   // rows ty*4..ty*4+3
    const int row0 = blockIdx.x * 32;

    float acc[4][4] = {};

    for (int kt = 0; kt < 128; kt += 32) {
        #pragma unroll
        for (int i = 0; i < 4; ++i) {
            int idx = tid + i * 256;
            int r = idx >> 5;
            int c4 = idx & 31;
            *(float4*)&ws[r][c4 * 4] = *(const float4*)&W[(kt + r) * D + c4 * 4];
        }
        {
            int r = tid >> 3;
            int c4 = tid & 7;
            int grow = row0 + r;
            float4 v = {0.f, 0.f, 0.f, 0.f};
            if (grow < M) v = *(const float4*)&A[grow * D + kt + c4 * 4];
            if (RELU) {
                v.x = fmaxf(v.x, 0.f); v.y = fmaxf(v.y, 0.f);
                v.z = fmaxf(v.z, 0.f); v.w = fmaxf(v.w, 0.f);
            }
            *(float4*)&xs[r][c4 * 4] = v;
        }
        __syncthreads();
        #pragma unroll
        for (int k = 0; k < 32; ++k) {
            float4 wv = *(float4*)&ws[k][tx * 4];
            float xv[4];
            #pragma unroll
            for (int i = 0; i < 4; ++i) xv[i] = xs[ty * 4 + i][k];
            #pragma unroll
            for (int i = 0; i < 4; ++i) {
                acc[i][0] += xv[i] * wv.x;
                acc[i][1] += xv[i] * wv.y;
                acc[i][2] += xv[i] * wv.z;
                acc[i][3] += xv[i] * wv.w;
            }
        }
        __syncthreads();
    }
    #pragma unroll
    for (int i = 0; i < 4; ++i) {
        int grow = row0 + ty * 4 + i;
        if (grow < M) {
            float dn = dinv[grow];
            float4 v = {acc[i][0] * dn, acc[i][1] * dn, acc[i][2] * dn, acc[i][3] * dn};
            *(float4*)&C[grow * D + tx * 4] = v;
        }
    }
}

// ---------------- CSR gather-aggregate ----------------
// out[n][:] = dinv[n] * ( sum_{s in in(n)} hn[s][:] + hn[n][:] ) + bias[:]
// hn already scaled by dinv[src]. One wave per node, float2/lane.
__global__ __launch_bounds__(256) void gather_kernel(const float* __restrict__ hn,
                                                     const float* __restrict__ dinv,
                                                     const int* __restrict__ offs,
                                                     const int* __restrict__ cnt,
                                                     const int* __restrict__ csr,
                                                     const float* __restrict__ bias,
                                                     float* __restrict__ out) {
    const int wid = threadIdx.x >> 6;       // wave in block: 0..3
    const int lane = threadIdx.x & 63;
    const int n = blockIdx.x * 4 + wid;
    if (n >= N_NODES) return;
    const int beg = offs[n];
    const int m = cnt[n];
    const int col = lane * 2;

    float ax = 0.f, ay = 0.f;
    int i = 0;
    for (; i + 4 <= m; i += 4) {
        int s0 = csr[beg + i];
        int s1 = csr[beg + i + 1];
        int s2 = csr[beg + i + 2];
        int s3 = csr[beg + i + 3];
        float2 v0 = *(const float2*)&hn[(size_t)s0 * D + col];
        float2 v1 = *(const float2*)&hn[(size_t)s1 * D + col];
        float2 v2 = *(const float2*)&hn[(size_t)s2 * D + col];
        float2 v3 = *(const float2*)&hn[(size_t)s3 * D + col];
        ax += v0.x + v1.x + v2.x + v3.x;
        ay += v0.y + v1.y + v2.y + v3.y;
    }
    for (; i < m; ++i) {
        int s = csr[beg + i];
        float2 v = *(const float2*)&hn[(size_t)s * D + col];
        ax += v.x;
        ay += v.y;
    }
    float dn = dinv[n];
    float2 hv = *(const float2*)&hn[(size_t)n * D + col];
    float2 bv = *(const float2*)&bias[col];
    float2 o = { dn * (ax + hv.x) + bv.x, dn * (ay + hv.y) + bv.y };
    *(float2*)&out[(size_t)n * D + col] = o;
}

extern "C" void kernel_launch(void* const* d_in, const int* in_sizes, int n_in,
                              void* d_out, int out_size, void* d_ws, size_t ws_size,
                              hipStream_t stream) {
    const float* x  = (const float*)d_in[0];
    const int*   ei = (const int*)d_in[1];     // [2, N_EDGES], int32 on device
    const float* W1 = (const float*)d_in[2];
    const float* b1 = (const float*)d_in[3];
    const float* W2 = (const float*)d_in[4];
    const float* b2 = (const float*)d_in[5];
    float* out = (float*)d_out;

    const int* src = ei;
    const int* dst = ei + N_EDGES;

    // workspace layout (4-byte units)
    char* wsb = (char*)d_ws;
    int*   cnt     = (int*)(wsb);                                // [50176]
    int*   cursor  = cnt + 50176;                                // [50176]
    int*   offs    = cursor + 50176;                             // [50176]
    float* dinv    = (float*)(offs + 50176);                     // [50176]
    int*   partial = (int*)(dinv + 50176);                       // [256]
    int*   csr     = partial + 256;                              // [800000]
    float* hn      = (float*)(csr + 800000);                     // [N,128]
    float* agg1    = hn + (size_t)N_NODES * D;                   // [N,128]

    const int B = 256;

    cnt_init_kernel<<<(N_NODES + B - 1) / B, B, 0, stream>>>(cnt);
    deg_count_kernel<<<(N_EDGES + B - 1) / B, B, 0, stream>>>(dst, cnt);
    blocksum_kernel<<<NBLK, B, 0, stream>>>(cnt, partial);
    scan_partials_kernel<<<1, B, 0, stream>>>(partial);
    scan_block_kernel<<<NBLK, B, 0, stream>>>(cnt, partial, offs, cursor, dinv);
    scatter_kernel<<<(N_EDGES + B - 1) / B, B, 0, stream>>>(src, dst, cursor, csr);

    const int gemm_grid = (N_NODES + 31) / 32;
    const int gather_grid = (N_NODES + 3) / 4;

    // layer 1: hn = (x @ W1) * dinv[row]
    gemm128_kernel<false><<<gemm_grid, B, 0, stream>>>(x, W1, dinv, hn, N_NODES);
    gather_kernel<<<gather_grid, B, 0, stream>>>(hn, dinv, offs, cnt, csr, b1, agg1);

    // layer 2: hn2 = (relu(agg1) @ W2) * dinv[row]   (reuses hn buffer)
    gemm128_kernel<true><<<gemm_grid, B, 0, stream>>>(agg1, W2, dinv, hn, N_NODES);
    gather_kernel<<<gather_grid, B, 0, stream>>>(hn, dinv, offs, cnt, csr, b2, out);
}

// Round 4
// 287.390 us; speedup vs baseline: 10.0009x; 1.1805x over previous
//
#include <hip/hip_runtime.h>

#define N_NODES 50000
#define N_EDGES 800000
#define D 128
#define NBLK 196   // ceil(50000/256)

typedef __attribute__((ext_vector_type(8))) short bf16x8;
typedef __attribute__((ext_vector_type(4))) float f32x4;

__device__ inline unsigned short f2bf(float f) {
    unsigned u = __float_as_uint(f);
    u += 0x7fffu + ((u >> 16) & 1u);   // round-to-nearest-even
    return (unsigned short)(u >> 16);
}
__device__ inline float bf2f(unsigned short h) {
    return __uint_as_float((unsigned)h << 16);
}

// ---------------- degree counting ----------------

__global__ void cnt_init_kernel(int* __restrict__ cnt) {
    int n = blockIdx.x * blockDim.x + threadIdx.x;
    if (n < N_NODES) cnt[n] = 0;
}

__global__ void deg_count_kernel(const int* __restrict__ dst, int* __restrict__ cnt) {
    int e = blockIdx.x * blockDim.x + threadIdx.x;
    if (e < N_EDGES) atomicAdd(&cnt[dst[e]], 1);
}

// ---------------- W prep: transpose + split-bf16 + swizzle ----------------
// Output per array: [hi 16384 elems][lo 16384 elems], element (k,col) stored at
// transposed index col*128+k, byte address XOR-swizzled: b ^= ((b>>8)&7)<<4.
__global__ void prepw_kernel(const float* __restrict__ W1, const float* __restrict__ W2,
                             unsigned short* __restrict__ Wt) {
    int tid = blockIdx.x * 256 + threadIdx.x;   // 0..32767
    int a = tid >> 14;
    int idx = tid & 16383;
    const float* W = a ? W2 : W1;
    float w = W[idx];
    unsigned short hi = f2bf(w);
    unsigned short lo = f2bf(w - bf2f(hi));
    int k = idx >> 7, col = idx & 127;
    int byte = (col * 128 + k) * 2;
    int swz = byte ^ (((byte >> 8) & 7) << 4);
    unsigned short* base = Wt + a * 32768;
    *(unsigned short*)((char*)base + swz) = hi;
    *(unsigned short*)((char*)(base + 16384) + swz) = lo;
}

// ---------------- hierarchical exclusive scan ----------------

__global__ __launch_bounds__(256) void blocksum_kernel(const int* __restrict__ cnt,
                                                       int* __restrict__ partial) {
    __shared__ int red[256];
    const int t = threadIdx.x;
    int i = blockIdx.x * 256 + t;
    red[t] = (i < N_NODES) ? cnt[i] : 0;
    __syncthreads();
    #pragma unroll
    for (int off = 128; off > 0; off >>= 1) {
        if (t < off) red[t] += red[t + off];
        __syncthreads();
    }
    if (t == 0) partial[blockIdx.x] = red[0];
}

__global__ __launch_bounds__(256) void scan_partials_kernel(int* __restrict__ partial) {
    __shared__ int s[256];
    const int t = threadIdx.x;
    int v = (t < NBLK) ? partial[t] : 0;
    s[t] = v;
    __syncthreads();
    #pragma unroll
    for (int off = 1; off < 256; off <<= 1) {
        int add = (t >= off) ? s[t - off] : 0;
        __syncthreads();
        s[t] += add;
        __syncthreads();
    }
    if (t < NBLK) partial[t] = s[t] - v;
}

__global__ __launch_bounds__(256) void scan_block_kernel(const int* __restrict__ cnt,
                                                         const int* __restrict__ partial,
                                                         int* __restrict__ offs,
                                                         int* __restrict__ cursor,
                                                         float* __restrict__ dinv) {
    __shared__ int s[256];
    const int t = threadIdx.x;
    int i = blockIdx.x * 256 + t;
    int v = (i < N_NODES) ? cnt[i] : 0;
    s[t] = v;
    __syncthreads();
    #pragma unroll
    for (int off = 1; off < 256; off <<= 1) {
        int add = (t >= off) ? s[t - off] : 0;
        __syncthreads();
        s[t] += add;
        __syncthreads();
    }
    if (i < N_NODES) {
        int o = s[t] - v + partial[blockIdx.x];
        offs[i] = o;
        cursor[i] = o;
        dinv[i] = rsqrtf((float)v + 1.0f);
    }
}

__global__ void scatter_kernel(const int* __restrict__ src, const int* __restrict__ dst,
                               int* __restrict__ cursor, int* __restrict__ csr) {
    int e = blockIdx.x * blockDim.x + threadIdx.x;
    if (e < N_EDGES) {
        int pos = atomicAdd(&cursor[dst[e]], 1);
        csr[pos] = src[e];
    }
}

// ---------------- split-bf16 MFMA GEMM ----------------
// Cb[row][col] (bf16) = ((relu?)A[row][:] @ W) * dinv[row]
// A@W ~= Ah@Wh + Ah@Wl + Al@Wh  (each bf16; error ~2^-17)
// Block: 64 rows x 128 cols, 4 waves (16 rows each). W staged in LDS (64KB).
template<bool RELU>
__global__ __launch_bounds__(256) void mfma_gemm_kernel(const float* __restrict__ A,
                                                        const unsigned short* __restrict__ Wt,
                                                        const float* __restrict__ dinv,
                                                        unsigned short* __restrict__ Cb,
                                                        int M) {
    __shared__ unsigned short lds[32768];   // 64 KB: [hi 32KB][lo 32KB], pre-swizzled
    const int tid = threadIdx.x;
    #pragma unroll
    for (int i = 0; i < 16; ++i) {
        int off = i * 4096 + tid * 16;
        *(uint4*)((char*)lds + off) = *(const uint4*)((const char*)Wt + off);
    }

    const int lane = tid & 63;
    const int wave = tid >> 6;
    const int c = lane & 15;    // A-row-in-wave / B-col-in-tile
    const int g = lane >> 4;    // k-group
    const int arow_i = blockIdx.x * 64 + wave * 16 + c;
    const bool inb = arow_i < M;
    const float* arow = A + (size_t)arow_i * D;

    // A fragments: row=lane&15, k = s*32 + g*8 + j
    bf16x8 ah[4], al[4];
    #pragma unroll
    for (int s = 0; s < 4; ++s) {
        int k0 = s * 32 + g * 8;
        float4 v0 = {0.f, 0.f, 0.f, 0.f}, v1 = {0.f, 0.f, 0.f, 0.f};
        if (inb) {
            v0 = *(const float4*)(arow + k0);
            v1 = *(const float4*)(arow + k0 + 4);
        }
        float av[8] = {v0.x, v0.y, v0.z, v0.w, v1.x, v1.y, v1.z, v1.w};
        #pragma unroll
        for (int j = 0; j < 8; ++j) {
            float f = av[j];
            if (RELU) f = fmaxf(f, 0.f);
            unsigned short h = f2bf(f);
            unsigned short l = f2bf(f - bf2f(h));
            ah[s][j] = (short)h;
            al[s][j] = (short)l;
        }
    }
    __syncthreads();

    f32x4 acc[8];
    #pragma unroll
    for (int t = 0; t < 8; ++t) { f32x4 z = {0.f, 0.f, 0.f, 0.f}; acc[t] = z; }

    const int xmask = (lane & 7) << 4;
    #pragma unroll
    for (int s = 0; s < 4; ++s) {
        int lowk = (s * 64 + g * 16) ^ xmask;   // swizzled low byte of B-frag addr
        #pragma unroll
        for (int t = 0; t < 8; ++t) {
            int off = t * 4096 + c * 256 + lowk;
            bf16x8 bh = *(const bf16x8*)((const char*)lds + off);
            bf16x8 bl = *(const bf16x8*)((const char*)lds + 32768 + off);
            acc[t] = __builtin_amdgcn_mfma_f32_16x16x32_bf16(al[s], bh, acc[t], 0, 0, 0);
            acc[t] = __builtin_amdgcn_mfma_f32_16x16x32_bf16(ah[s], bl, acc[t], 0, 0, 0);
            acc[t] = __builtin_amdgcn_mfma_f32_16x16x32_bf16(ah[s], bh, acc[t], 0, 0, 0);
        }
    }

    // D layout: col = lane&15, row = 4*g + reg
    const int r0 = blockIdx.x * 64 + wave * 16 + g * 4;
    float dn[4];
    #pragma unroll
    for (int r = 0; r < 4; ++r) dn[r] = (r0 + r < M) ? dinv[r0 + r] : 0.f;
    #pragma unroll
    for (int t = 0; t < 8; ++t) {
        #pragma unroll
        for (int r = 0; r < 4; ++r) {
            int grow = r0 + r;
            if (grow < M) Cb[(size_t)grow * D + t * 16 + c] = f2bf(acc[t][r] * dn[r]);
        }
    }
}

// ---------------- CSR gather-aggregate (bf16 hn) ----------------
// out[n][:] = dinv[n] * ( sum_{s in in(n)} hn[s][:] + hn[n][:] ) + bias[:]
__global__ __launch_bounds__(256) void gather_kernel(const unsigned short* __restrict__ hnb,
                                                     const float* __restrict__ dinv,
                                                     const int* __restrict__ offs,
                                                     const int* __restrict__ cnt,
                                                     const int* __restrict__ csr,
                                                     const float* __restrict__ bias,
                                                     float* __restrict__ out) {
    const int wid = threadIdx.x >> 6;
    const int lane = threadIdx.x & 63;
    const int n = blockIdx.x * 4 + wid;
    if (n >= N_NODES) return;
    const int beg = offs[n];
    const int m = cnt[n];
    const int col = lane * 2;

    float ax = 0.f, ay = 0.f;
    int i = 0;
    for (; i + 4 <= m; i += 4) {
        int s0 = csr[beg + i];
        int s1 = csr[beg + i + 1];
        int s2 = csr[beg + i + 2];
        int s3 = csr[beg + i + 3];
        unsigned v0 = *(const unsigned*)(hnb + (size_t)s0 * D + col);
        unsigned v1 = *(const unsigned*)(hnb + (size_t)s1 * D + col);
        unsigned v2 = *(const unsigned*)(hnb + (size_t)s2 * D + col);
        unsigned v3 = *(const unsigned*)(hnb + (size_t)s3 * D + col);
        ax += __uint_as_float(v0 << 16) + __uint_as_float(v1 << 16) +
              __uint_as_float(v2 << 16) + __uint_as_float(v3 << 16);
        ay += __uint_as_float(v0 & 0xffff0000u) + __uint_as_float(v1 & 0xffff0000u) +
              __uint_as_float(v2 & 0xffff0000u) + __uint_as_float(v3 & 0xffff0000u);
    }
    for (; i < m; ++i) {
        int s = csr[beg + i];
        unsigned v = *(const unsigned*)(hnb + (size_t)s * D + col);
        ax += __uint_as_float(v << 16);
        ay += __uint_as_float(v & 0xffff0000u);
    }
    float dn = dinv[n];
    unsigned hv = *(const unsigned*)(hnb + (size_t)n * D + col);
    float2 bv = *(const float2*)&bias[col];
    float ox = dn * (ax + __uint_as_float(hv << 16)) + bv.x;
    float oy = dn * (ay + __uint_as_float(hv & 0xffff0000u)) + bv.y;
    float2 o = {ox, oy};
    *(float2*)&out[(size_t)n * D + col] = o;
}

extern "C" void kernel_launch(void* const* d_in, const int* in_sizes, int n_in,
                              void* d_out, int out_size, void* d_ws, size_t ws_size,
                              hipStream_t stream) {
    const float* x  = (const float*)d_in[0];
    const int*   ei = (const int*)d_in[1];
    const float* W1 = (const float*)d_in[2];
    const float* b1 = (const float*)d_in[3];
    const float* W2 = (const float*)d_in[4];
    const float* b2 = (const float*)d_in[5];
    float* out = (float*)d_out;

    const int* src = ei;
    const int* dst = ei + N_EDGES;

    // workspace layout
    char* wsb = (char*)d_ws;
    int*   cnt     = (int*)(wsb);                          // [50176]
    int*   cursor  = cnt + 50176;
    int*   offs    = cursor + 50176;
    float* dinv    = (float*)(offs + 50176);
    int*   partial = (int*)(dinv + 50176);                 // [256]
    int*   csr     = partial + 256;                        // [800000]
    unsigned short* Wt = (unsigned short*)(csr + 800000);  // [2*32768] = 128 KB
    unsigned short* hn = Wt + 65536;                       // [N*128] bf16 = 12.8 MB
    float* agg1 = (float*)(hn + (size_t)N_NODES * D + 64); // [N*128] f32 = 25.6 MB

    const int B = 256;

    prepw_kernel<<<128, B, 0, stream>>>(W1, W2, Wt);
    cnt_init_kernel<<<(N_NODES + B - 1) / B, B, 0, stream>>>(cnt);
    deg_count_kernel<<<(N_EDGES + B - 1) / B, B, 0, stream>>>(dst, cnt);
    blocksum_kernel<<<NBLK, B, 0, stream>>>(cnt, partial);
    scan_partials_kernel<<<1, B, 0, stream>>>(partial);
    scan_block_kernel<<<NBLK, B, 0, stream>>>(cnt, partial, offs, cursor, dinv);
    scatter_kernel<<<(N_EDGES + B - 1) / B, B, 0, stream>>>(src, dst, cursor, csr);

    const int gemm_grid = (N_NODES + 63) / 64;
    const int gather_grid = (N_NODES + 3) / 4;

    // layer 1: hn = bf16( (x @ W1) * dinv[row] )
    mfma_gemm_kernel<false><<<gemm_grid, B, 0, stream>>>(x, Wt, dinv, hn, N_NODES);
    gather_kernel<<<gather_grid, B, 0, stream>>>(hn, dinv, offs, cnt, csr, b1, agg1);

    // layer 2: hn = bf16( (relu(agg1) @ W2) * dinv[row] )
    mfma_gemm_kernel<true><<<gemm_grid, B, 0, stream>>>(agg1, Wt + 32768, dinv, hn, N_NODES);
    gather_kernel<<<gather_grid, B, 0, stream>>>(hn, dinv, offs, cnt, csr, b2, out);
}

// Round 5
// 231.091 us; speedup vs baseline: 12.4374x; 1.2436x over previous
//
#include <hip/hip_runtime.h>

#define N_NODES 50000
#define N_EDGES 800000
#define D 128
#define NBUK 196     // buckets of 256 nodes (dst>>8)
#define HB 128       // histogram/staging blocks
#define EPB 6250     // edges per block: 128*6250 = 800000 exactly

typedef __attribute__((ext_vector_type(8))) short bf16x8;
typedef __attribute__((ext_vector_type(4))) float f32x4;

__device__ inline unsigned short f2bf(float f) {
    unsigned u = __float_as_uint(f);
    u += 0x7fffu + ((u >> 16) & 1u);   // round-to-nearest-even
    return (unsigned short)(u >> 16);
}
__device__ inline float bf2f(unsigned short h) {
    return __uint_as_float((unsigned)h << 16);
}

// ---------------- W prep: transpose + split-bf16 + swizzle ----------------
__global__ void prepw_kernel(const float* __restrict__ W1, const float* __restrict__ W2,
                             unsigned short* __restrict__ Wt) {
    int tid = blockIdx.x * 256 + threadIdx.x;   // 0..32767
    int a = tid >> 14;
    int idx = tid & 16383;
    const float* W = a ? W2 : W1;
    float w = W[idx];
    unsigned short hi = f2bf(w);
    unsigned short lo = f2bf(w - bf2f(hi));
    int k = idx >> 7, col = idx & 127;
    int byte = (col * 128 + k) * 2;
    int swz = byte ^ (((byte >> 8) & 7) << 4);
    unsigned short* base = Wt + a * 32768;
    *(unsigned short*)((char*)base + swz) = hi;
    *(unsigned short*)((char*)(base + 16384) + swz) = lo;
}

// ---------------- bucketed CSR build ----------------
// phase 1a: per-block bucket histogram (no global atomics)
__global__ __launch_bounds__(256) void khist_kernel(const int* __restrict__ dst,
                                                    int* __restrict__ H) {
    __shared__ int hist[NBUK];
    const int t = threadIdx.x;
    if (t < NBUK) hist[t] = 0;
    __syncthreads();
    const int e0 = blockIdx.x * EPB;
    for (int i = t; i < EPB; i += 256)
        atomicAdd(&hist[dst[e0 + i] >> 8], 1);
    __syncthreads();
    if (t < NBUK) H[blockIdx.x * NBUK + t] = hist[t];
}

// phase 1b: bucket bases + per-block staging bases
__global__ __launch_bounds__(256) void kscan_kernel(const int* __restrict__ H,
                                                    int* __restrict__ B,
                                                    int* __restrict__ bbase,
                                                    int* __restrict__ bsize) {
    __shared__ int s[256];
    const int t = threadIdx.x;
    int sum = 0;
    if (t < NBUK)
        for (int blk = 0; blk < HB; ++blk) sum += H[blk * NBUK + t];
    s[t] = sum;
    __syncthreads();
    #pragma unroll
    for (int off = 1; off < 256; off <<= 1) {
        int add = (t >= off) ? s[t - off] : 0;
        __syncthreads();
        s[t] += add;
        __syncthreads();
    }
    int base = s[t] - sum;   // exclusive
    if (t < NBUK) {
        bbase[t] = base;
        bsize[t] = sum;
        int run = base;
        for (int blk = 0; blk < HB; ++blk) {
            B[blk * NBUK + t] = run;
            run += H[blk * NBUK + t];
        }
    }
}

// phase 1c: scatter packed edges into block-exclusive staging sub-ranges
__global__ __launch_bounds__(256) void kstage_kernel(const int* __restrict__ src,
                                                     const int* __restrict__ dst,
                                                     const int* __restrict__ B,
                                                     unsigned* __restrict__ stage) {
    __shared__ int cur[NBUK];
    const int t = threadIdx.x;
    if (t < NBUK) cur[t] = B[blockIdx.x * NBUK + t];
    __syncthreads();
    const int e0 = blockIdx.x * EPB;
    for (int i = t; i < EPB; i += 256) {
        int d = dst[e0 + i];
        int s = src[e0 + i];
        int pos = atomicAdd(&cur[d >> 8], 1);
        stage[pos] = (unsigned)s | ((unsigned)(d & 255) << 16);
    }
}

// phase 2: per-bucket exact CSR + deg/dinv/offs (all writes block-exclusive)
__global__ __launch_bounds__(256) void kfinal_kernel(const unsigned* __restrict__ stage,
                                                     const int* __restrict__ bbase,
                                                     const int* __restrict__ bsize,
                                                     int* __restrict__ cnt,
                                                     int* __restrict__ offs,
                                                     float* __restrict__ dinv,
                                                     int* __restrict__ csr) {
    __shared__ int hist[256];
    __shared__ int s[256];
    const int t = threadIdx.x;
    const int k = blockIdx.x;
    const int base = bbase[k];
    const int size = bsize[k];
    hist[t] = 0;
    __syncthreads();
    for (int i = t; i < size; i += 256)
        atomicAdd(&hist[stage[base + i] >> 16], 1);
    __syncthreads();
    int deg = hist[t];
    s[t] = deg;
    __syncthreads();
    #pragma unroll
    for (int off = 1; off < 256; off <<= 1) {
        int add = (t >= off) ? s[t - off] : 0;
        __syncthreads();
        s[t] += add;
        __syncthreads();
    }
    int excl = s[t] - deg;
    int node = k * 256 + t;
    if (node < N_NODES) {
        cnt[node] = deg;
        offs[node] = base + excl;
        dinv[node] = rsqrtf((float)deg + 1.0f);
    }
    hist[t] = base + excl;   // reuse as cursor
    __syncthreads();
    for (int i = t; i < size; i += 256) {
        unsigned v = stage[base + i];
        int pos = atomicAdd(&hist[v >> 16], 1);
        csr[pos] = (int)(v & 0xffffu);
    }
}

// ---------------- split-bf16 MFMA GEMM ----------------
// Cb[row][col] (bf16) = (relu?)A[row][:] @ W    (no dinv scaling)
template<bool RELU>
__global__ __launch_bounds__(256) void mfma_gemm_kernel(const float* __restrict__ A,
                                                        const unsigned short* __restrict__ Wt,
                                                        unsigned short* __restrict__ Cb,
                                                        int M) {
    __shared__ unsigned short lds[32768];   // 64 KB: [hi 32KB][lo 32KB], pre-swizzled
    const int tid = threadIdx.x;
    #pragma unroll
    for (int i = 0; i < 16; ++i) {
        int off = i * 4096 + tid * 16;
        *(uint4*)((char*)lds + off) = *(const uint4*)((const char*)Wt + off);
    }

    const int lane = tid & 63;
    const int wave = tid >> 6;
    const int c = lane & 15;
    const int g = lane >> 4;
    const int arow_i = blockIdx.x * 64 + wave * 16 + c;
    const bool inb = arow_i < M;
    const float* arow = A + (size_t)arow_i * D;

    bf16x8 ah[4], al[4];
    #pragma unroll
    for (int s = 0; s < 4; ++s) {
        int k0 = s * 32 + g * 8;
        float4 v0 = {0.f, 0.f, 0.f, 0.f}, v1 = {0.f, 0.f, 0.f, 0.f};
        if (inb) {
            v0 = *(const float4*)(arow + k0);
            v1 = *(const float4*)(arow + k0 + 4);
        }
        float av[8] = {v0.x, v0.y, v0.z, v0.w, v1.x, v1.y, v1.z, v1.w};
        #pragma unroll
        for (int j = 0; j < 8; ++j) {
            float f = av[j];
            if (RELU) f = fmaxf(f, 0.f);
            unsigned short h = f2bf(f);
            unsigned short l = f2bf(f - bf2f(h));
            ah[s][j] = (short)h;
            al[s][j] = (short)l;
        }
    }
    __syncthreads();

    f32x4 acc[8];
    #pragma unroll
    for (int t = 0; t < 8; ++t) { f32x4 z = {0.f, 0.f, 0.f, 0.f}; acc[t] = z; }

    const int xmask = (lane & 7) << 4;
    #pragma unroll
    for (int s = 0; s < 4; ++s) {
        int lowk = (s * 64 + g * 16) ^ xmask;
        #pragma unroll
        for (int t = 0; t < 8; ++t) {
            int off = t * 4096 + c * 256 + lowk;
            bf16x8 bh = *(const bf16x8*)((const char*)lds + off);
            bf16x8 bl = *(const bf16x8*)((const char*)lds + 32768 + off);
            acc[t] = __builtin_amdgcn_mfma_f32_16x16x32_bf16(al[s], bh, acc[t], 0, 0, 0);
            acc[t] = __builtin_amdgcn_mfma_f32_16x16x32_bf16(ah[s], bl, acc[t], 0, 0, 0);
            acc[t] = __builtin_amdgcn_mfma_f32_16x16x32_bf16(ah[s], bh, acc[t], 0, 0, 0);
        }
    }

    const int r0 = blockIdx.x * 64 + wave * 16 + g * 4;
    #pragma unroll
    for (int t = 0; t < 8; ++t) {
        #pragma unroll
        for (int r = 0; r < 4; ++r) {
            int grow = r0 + r;
            if (grow < M) Cb[(size_t)grow * D + t * 16 + c] = f2bf(acc[t][r]);
        }
    }
}

// ---------------- CSR gather-aggregate (bf16 hn, per-edge dinv[src]) ----------------
// out[n][:] = dinv[n] * ( sum_s dinv[s]*hn[s][:] + dinv[n]*hn[n][:] ) + bias[:]
__global__ __launch_bounds__(256) void gather_kernel(const unsigned short* __restrict__ hnb,
                                                     const float* __restrict__ dinv,
                                                     const int* __restrict__ offs,
                                                     const int* __restrict__ cnt,
                                                     const int* __restrict__ csr,
                                                     const float* __restrict__ bias,
                                                     float* __restrict__ out) {
    const int wid = threadIdx.x >> 6;
    const int lane = threadIdx.x & 63;
    const int n = blockIdx.x * 4 + wid;
    if (n >= N_NODES) return;
    const int beg = offs[n];
    const int m = cnt[n];
    const int col = lane * 2;

    float ax = 0.f, ay = 0.f;
    int i = 0;
    for (; i + 4 <= m; i += 4) {
        int s0 = csr[beg + i];
        int s1 = csr[beg + i + 1];
        int s2 = csr[beg + i + 2];
        int s3 = csr[beg + i + 3];
        float w0 = dinv[s0], w1 = dinv[s1], w2 = dinv[s2], w3 = dinv[s3];
        unsigned v0 = *(const unsigned*)(hnb + (size_t)s0 * D + col);
        unsigned v1 = *(const unsigned*)(hnb + (size_t)s1 * D + col);
        unsigned v2 = *(const unsigned*)(hnb + (size_t)s2 * D + col);
        unsigned v3 = *(const unsigned*)(hnb + (size_t)s3 * D + col);
        ax = fmaf(w0, __uint_as_float(v0 << 16), ax);
        ax = fmaf(w1, __uint_as_float(v1 << 16), ax);
        ax = fmaf(w2, __uint_as_float(v2 << 16), ax);
        ax = fmaf(w3, __uint_as_float(v3 << 16), ax);
        ay = fmaf(w0, __uint_as_float(v0 & 0xffff0000u), ay);
        ay = fmaf(w1, __uint_as_float(v1 & 0xffff0000u), ay);
        ay = fmaf(w2, __uint_as_float(v2 & 0xffff0000u), ay);
        ay = fmaf(w3, __uint_as_float(v3 & 0xffff0000u), ay);
    }
    for (; i < m; ++i) {
        int s = csr[beg + i];
        float w = dinv[s];
        unsigned v = *(const unsigned*)(hnb + (size_t)s * D + col);
        ax = fmaf(w, __uint_as_float(v << 16), ax);
        ay = fmaf(w, __uint_as_float(v & 0xffff0000u), ay);
    }
    float dn = dinv[n];
    float dn2 = dn * dn;
    unsigned hv = *(const unsigned*)(hnb + (size_t)n * D + col);
    float2 bv = *(const float2*)&bias[col];
    float ox = fmaf(dn, ax, fmaf(dn2, __uint_as_float(hv << 16), bv.x));
    float oy = fmaf(dn, ay, fmaf(dn2, __uint_as_float(hv & 0xffff0000u), bv.y));
    float2 o = {ox, oy};
    *(float2*)&out[(size_t)n * D + col] = o;
}

extern "C" void kernel_launch(void* const* d_in, const int* in_sizes, int n_in,
                              void* d_out, int out_size, void* d_ws, size_t ws_size,
                              hipStream_t stream) {
    const float* x  = (const float*)d_in[0];
    const int*   ei = (const int*)d_in[1];
    const float* W1 = (const float*)d_in[2];
    const float* b1 = (const float*)d_in[3];
    const float* W2 = (const float*)d_in[4];
    const float* b2 = (const float*)d_in[5];
    float* out = (float*)d_out;

    const int* src = ei;
    const int* dst = ei + N_EDGES;

    // workspace layout (int units unless noted)
    int* wsi = (int*)d_ws;
    int*      cnt   = wsi;                        // [50176]
    int*      offs  = cnt + 50176;                // [50176]
    float*    dinv  = (float*)(offs + 50176);     // [50176]
    int*      bbase = (int*)(dinv + 50176);       // [256]
    int*      bsize = bbase + 256;                // [256]
    int*      H     = bsize + 256;                // [HB*NBUK = 25088]
    int*      B     = H + 25088;                  // [25088]
    unsigned* stage = (unsigned*)(B + 25088);     // [800000]
    int*      csr   = (int*)(stage + 800000);     // [800000]
    unsigned short* Wt = (unsigned short*)(csr + 800000);   // [2*32768]
    unsigned short* hn = Wt + 65536;                        // [N*128] bf16
    float* agg1 = (float*)(hn + (size_t)N_NODES * D + 64);  // [N*128] f32

    const int Bt = 256;

    prepw_kernel<<<128, Bt, 0, stream>>>(W1, W2, Wt);

    // CSR build (bucketed counting sort)
    khist_kernel<<<HB, Bt, 0, stream>>>(dst, H);
    kscan_kernel<<<1, Bt, 0, stream>>>(H, B, bbase, bsize);
    kstage_kernel<<<HB, Bt, 0, stream>>>(src, dst, B, stage);
    kfinal_kernel<<<NBUK, Bt, 0, stream>>>(stage, bbase, bsize, cnt, offs, dinv, csr);

    const int gemm_grid = (N_NODES + 63) / 64;
    const int gather_grid = (N_NODES + 3) / 4;

    // layer 1: hn = bf16(x @ W1)
    mfma_gemm_kernel<false><<<gemm_grid, Bt, 0, stream>>>(x, Wt, hn, N_NODES);
    gather_kernel<<<gather_grid, Bt, 0, stream>>>(hn, dinv, offs, cnt, csr, b1, agg1);

    // layer 2: hn = bf16(relu(agg1) @ W2)
    mfma_gemm_kernel<true><<<gemm_grid, Bt, 0, stream>>>(agg1, Wt + 32768, hn, N_NODES);
    gather_kernel<<<gather_grid, Bt, 0, stream>>>(hn, dinv, offs, cnt, csr, b2, out);
}

// Round 9
// 212.479 us; speedup vs baseline: 13.5268x; 1.0876x over previous
//
#include <hip/hip_runtime.h>

#define N_NODES 50000
#define N_EDGES 800000
#define D 128
#define NBUK 196     // buckets of 256 nodes (dst>>8)
#define HB 128       // histogram/staging blocks
#define EPB 6250     // edges per block: 128*6250 = 800000 exactly

typedef __attribute__((ext_vector_type(8))) short bf16x8;
typedef __attribute__((ext_vector_type(4))) float f32x4;

__device__ inline unsigned short f2bf(float f) {
    unsigned u = __float_as_uint(f);
    u += 0x7fffu + ((u >> 16) & 1u);   // round-to-nearest-even
    return (unsigned short)(u >> 16);
}
__device__ inline float bf2f(unsigned short h) {
    return __uint_as_float((unsigned)h << 16);
}

// ---------------- merged: W prep (blocks 0..127) + bucket histogram (blocks 128..255) ----
__global__ __launch_bounds__(256) void prep_hist_kernel(const float* __restrict__ W1,
                                                        const float* __restrict__ W2,
                                                        unsigned short* __restrict__ Wt,
                                                        const int* __restrict__ dst,
                                                        int* __restrict__ H) {
    __shared__ int hist[NBUK];
    const int b = blockIdx.x;
    const int t = threadIdx.x;
    if (b < 128) {
        // W prep: transpose + split-bf16 + XOR swizzle
        int tid = b * 256 + t;          // 0..32767
        int a = tid >> 14;
        int idx = tid & 16383;
        const float* W = a ? W2 : W1;
        float w = W[idx];
        unsigned short hi = f2bf(w);
        unsigned short lo = f2bf(w - bf2f(hi));
        int k = idx >> 7, col = idx & 127;
        int byte = (col * 128 + k) * 2;
        int swz = byte ^ (((byte >> 8) & 7) << 4);
        unsigned short* base = Wt + a * 32768;
        *(unsigned short*)((char*)base + swz) = hi;
        *(unsigned short*)((char*)(base + 16384) + swz) = lo;
    } else {
        // per-block bucket histogram (no global atomics)
        const int blk = b - 128;
        if (t < NBUK) hist[t] = 0;
        __syncthreads();
        const int e0 = blk * EPB;
        for (int i = t; i < EPB; i += 256)
            atomicAdd(&hist[dst[e0 + i] >> 8], 1);
        __syncthreads();
        if (t < NBUK) H[blk * NBUK + t] = hist[t];
    }
}

// ---------------- bucket bases + per-block staging bases ----------------
__global__ __launch_bounds__(256) void kscan_kernel(const int* __restrict__ H,
                                                    int* __restrict__ B,
                                                    int* __restrict__ bbase,
                                                    int* __restrict__ bsize) {
    __shared__ int s[256];
    const int t = threadIdx.x;
    int sum = 0;
    if (t < NBUK)
        for (int blk = 0; blk < HB; ++blk) sum += H[blk * NBUK + t];
    s[t] = sum;
    __syncthreads();
    #pragma unroll
    for (int off = 1; off < 256; off <<= 1) {
        int add = (t >= off) ? s[t - off] : 0;
        __syncthreads();
        s[t] += add;
        __syncthreads();
    }
    int base = s[t] - sum;   // exclusive
    if (t < NBUK) {
        bbase[t] = base;
        bsize[t] = sum;
        int run = base;
        for (int blk = 0; blk < HB; ++blk) {
            B[blk * NBUK + t] = run;
            run += H[blk * NBUK + t];
        }
    }
}

// ---------------- scatter packed edges into block-exclusive staging sub-ranges ---------
__global__ __launch_bounds__(256) void kstage_kernel(const int* __restrict__ src,
                                                     const int* __restrict__ dst,
                                                     const int* __restrict__ B,
                                                     unsigned* __restrict__ stage) {
    __shared__ int cur[NBUK];
    const int t = threadIdx.x;
    if (t < NBUK) cur[t] = B[blockIdx.x * NBUK + t];
    __syncthreads();
    const int e0 = blockIdx.x * EPB;
    for (int i = t; i < EPB; i += 256) {
        int d = dst[e0 + i];
        int s = src[e0 + i];
        int pos = atomicAdd(&cur[d >> 8], 1);
        stage[pos] = (unsigned)s | ((unsigned)(d & 255) << 16);
    }
}

// ---------------- merged: gemm1 (blocks 0..781) + kfinal (blocks 782..977) -------------
// gemm: Cb[row][col] (bf16) = A[row][:] @ W  via split-bf16 MFMA (3 mfma/tile)
// kfinal: per-bucket CSR + deg/dinv/offs (block-exclusive writes)
__global__ __launch_bounds__(256) void gemm1_final_kernel(
        const float* __restrict__ A, const unsigned short* __restrict__ Wt,
        unsigned short* __restrict__ Cb, int M, int ngemm,
        const unsigned* __restrict__ stage, const int* __restrict__ bbase,
        const int* __restrict__ bsize, int* __restrict__ cnt, int* __restrict__ offs,
        float* __restrict__ dinv, int* __restrict__ csr) {
    __shared__ char smem[65536];
    const int tid = threadIdx.x;

    if ((int)blockIdx.x < ngemm) {
        // ---------- GEMM path ----------
        unsigned short* lds = (unsigned short*)smem;   // [hi 32KB][lo 32KB], pre-swizzled
        #pragma unroll
        for (int i = 0; i < 16; ++i) {
            int off = i * 4096 + tid * 16;
            *(uint4*)((char*)lds + off) = *(const uint4*)((const char*)Wt + off);
        }
        const int lane = tid & 63;
        const int wave = tid >> 6;
        const int c = lane & 15;
        const int g = lane >> 4;
        const int arow_i = blockIdx.x * 64 + wave * 16 + c;
        const bool inb = arow_i < M;
        const float* arow = A + (size_t)arow_i * D;

        bf16x8 ah[4], al[4];
        #pragma unroll
        for (int s = 0; s < 4; ++s) {
            int k0 = s * 32 + g * 8;
            float4 v0 = {0.f, 0.f, 0.f, 0.f}, v1 = {0.f, 0.f, 0.f, 0.f};
            if (inb) {
                v0 = *(const float4*)(arow + k0);
                v1 = *(const float4*)(arow + k0 + 4);
            }
            float av[8] = {v0.x, v0.y, v0.z, v0.w, v1.x, v1.y, v1.z, v1.w};
            #pragma unroll
            for (int j = 0; j < 8; ++j) {
                float f = av[j];
                unsigned short h = f2bf(f);
                unsigned short l = f2bf(f - bf2f(h));
                ah[s][j] = (short)h;
                al[s][j] = (short)l;
            }
        }
        __syncthreads();

        f32x4 acc[8];
        #pragma unroll
        for (int t = 0; t < 8; ++t) { f32x4 z = {0.f, 0.f, 0.f, 0.f}; acc[t] = z; }

        const int xmask = (lane & 7) << 4;
        #pragma unroll
        for (int s = 0; s < 4; ++s) {
            int lowk = (s * 64 + g * 16) ^ xmask;
            #pragma unroll
            for (int t = 0; t < 8; ++t) {
                int off = t * 4096 + c * 256 + lowk;
                bf16x8 bh = *(const bf16x8*)((const char*)lds + off);
                bf16x8 bl = *(const bf16x8*)((const char*)lds + 32768 + off);
                acc[t] = __builtin_amdgcn_mfma_f32_16x16x32_bf16(al[s], bh, acc[t], 0, 0, 0);
                acc[t] = __builtin_amdgcn_mfma_f32_16x16x32_bf16(ah[s], bl, acc[t], 0, 0, 0);
                acc[t] = __builtin_amdgcn_mfma_f32_16x16x32_bf16(ah[s], bh, acc[t], 0, 0, 0);
            }
        }

        const int r0 = blockIdx.x * 64 + wave * 16 + g * 4;
        #pragma unroll
        for (int t = 0; t < 8; ++t) {
            #pragma unroll
            for (int r = 0; r < 4; ++r) {
                int grow = r0 + r;
                if (grow < M) Cb[(size_t)grow * D + t * 16 + c] = f2bf(acc[t][r]);
            }
        }
    } else {
        // ---------- kfinal path ----------
        int* hist = (int*)smem;          // [256]
        int* s    = hist + 256;          // [256]
        const int t = tid;
        const int k = blockIdx.x - ngemm;
        const int base = bbase[k];
        const int size = bsize[k];
        hist[t] = 0;
        __syncthreads();
        for (int i = t; i < size; i += 256)
            atomicAdd(&hist[stage[base + i] >> 16], 1);
        __syncthreads();
        int deg = hist[t];
        s[t] = deg;
        __syncthreads();
        #pragma unroll
        for (int off = 1; off < 256; off <<= 1) {
            int add = (t >= off) ? s[t - off] : 0;
            __syncthreads();
            s[t] += add;
            __syncthreads();
        }
        int excl = s[t] - deg;
        int node = k * 256 + t;
        if (node < N_NODES) {
            cnt[node] = deg;
            offs[node] = base + excl;
            dinv[node] = rsqrtf((float)deg + 1.0f);
        }
        hist[t] = base + excl;   // reuse as cursor
        __syncthreads();
        for (int i = t; i < size; i += 256) {
            unsigned v = stage[base + i];
            int pos = atomicAdd(&hist[v >> 16], 1);
            csr[pos] = (int)(v & 0xffffu);
        }
    }
}

// ---------------- standalone split-bf16 MFMA GEMM (layer 2, relu on load) ---------------
__global__ __launch_bounds__(256) void mfma_gemm_relu_kernel(const float* __restrict__ A,
                                                             const unsigned short* __restrict__ Wt,
                                                             unsigned short* __restrict__ Cb,
                                                             int M) {
    __shared__ unsigned short lds[32768];
    const int tid = threadIdx.x;
    #pragma unroll
    for (int i = 0; i < 16; ++i) {
        int off = i * 4096 + tid * 16;
        *(uint4*)((char*)lds + off) = *(const uint4*)((const char*)Wt + off);
    }
    const int lane = tid & 63;
    const int wave = tid >> 6;
    const int c = lane & 15;
    const int g = lane >> 4;
    const int arow_i = blockIdx.x * 64 + wave * 16 + c;
    const bool inb = arow_i < M;
    const float* arow = A + (size_t)arow_i * D;

    bf16x8 ah[4], al[4];
    #pragma unroll
    for (int s = 0; s < 4; ++s) {
        int k0 = s * 32 + g * 8;
        float4 v0 = {0.f, 0.f, 0.f, 0.f}, v1 = {0.f, 0.f, 0.f, 0.f};
        if (inb) {
            v0 = *(const float4*)(arow + k0);
            v1 = *(const float4*)(arow + k0 + 4);
        }
        float av[8] = {v0.x, v0.y, v0.z, v0.w, v1.x, v1.y, v1.z, v1.w};
        #pragma unroll
        for (int j = 0; j < 8; ++j) {
            float f = fmaxf(av[j], 0.f);
            unsigned short h = f2bf(f);
            unsigned short l = f2bf(f - bf2f(h));
            ah[s][j] = (short)h;
            al[s][j] = (short)l;
        }
    }
    __syncthreads();

    f32x4 acc[8];
    #pragma unroll
    for (int t = 0; t < 8; ++t) { f32x4 z = {0.f, 0.f, 0.f, 0.f}; acc[t] = z; }

    const int xmask = (lane & 7) << 4;
    #pragma unroll
    for (int s = 0; s < 4; ++s) {
        int lowk = (s * 64 + g * 16) ^ xmask;
        #pragma unroll
        for (int t = 0; t < 8; ++t) {
            int off = t * 4096 + c * 256 + lowk;
            bf16x8 bh = *(const bf16x8*)((const char*)lds + off);
            bf16x8 bl = *(const bf16x8*)((const char*)lds + 32768 + off);
            acc[t] = __builtin_amdgcn_mfma_f32_16x16x32_bf16(al[s], bh, acc[t], 0, 0, 0);
            acc[t] = __builtin_amdgcn_mfma_f32_16x16x32_bf16(ah[s], bl, acc[t], 0, 0, 0);
            acc[t] = __builtin_amdgcn_mfma_f32_16x16x32_bf16(ah[s], bh, acc[t], 0, 0, 0);
        }
    }

    const int r0 = blockIdx.x * 64 + wave * 16 + g * 4;
    #pragma unroll
    for (int t = 0; t < 8; ++t) {
        #pragma unroll
        for (int r = 0; r < 4; ++r) {
            int grow = r0 + r;
            if (grow < M) Cb[(size_t)grow * D + t * 16 + c] = f2bf(acc[t][r]);
        }
    }
}

// ---------------- CSR gather-aggregate (bf16 hn, per-edge dinv[src]) ----------------
// out[n][:] = dinv[n] * sum_s dinv[s]*hn[s][:] + dinv[n]^2*hn[n][:] + bias[:]
__global__ __launch_bounds__(256) void gather_kernel(const unsigned short* __restrict__ hnb,
                                                     const float* __restrict__ dinv,
                                                     const int* __restrict__ offs,
                                                     const int* __restrict__ cnt,
                                                     const int* __restrict__ csr,
                                                     const float* __restrict__ bias,
                                                     float* __restrict__ out) {
    const int wid = threadIdx.x >> 6;
    const int lane = threadIdx.x & 63;
    const int n = blockIdx.x * 4 + wid;
    if (n >= N_NODES) return;
    const int beg = offs[n];
    const int m = cnt[n];
    const int col = lane * 2;

    float ax = 0.f, ay = 0.f;
    int i = 0;
    for (; i + 8 <= m; i += 8) {
        int sidx[8];
        #pragma unroll
        for (int j = 0; j < 8; ++j) sidx[j] = csr[beg + i + j];
        float w[8];
        unsigned v[8];
        #pragma unroll
        for (int j = 0; j < 8; ++j) {
            w[j] = dinv[sidx[j]];
            v[j] = *(const unsigned*)(hnb + (size_t)sidx[j] * D + col);
        }
        #pragma unroll
        for (int j = 0; j < 8; ++j) {
            ax = fmaf(w[j], __uint_as_float(v[j] << 16), ax);
            ay = fmaf(w[j], __uint_as_float(v[j] & 0xffff0000u), ay);
        }
    }
    for (; i + 4 <= m; i += 4) {
        int sidx[4];
        #pragma unroll
        for (int j = 0; j < 4; ++j) sidx[j] = csr[beg + i + j];
        #pragma unroll
        for (int j = 0; j < 4; ++j) {
            float w = dinv[sidx[j]];
            unsigned v = *(const unsigned*)(hnb + (size_t)sidx[j] * D + col);
            ax = fmaf(w, __uint_as_float(v << 16), ax);
            ay = fmaf(w, __uint_as_float(v & 0xffff0000u), ay);
        }
    }
    for (; i < m; ++i) {
        int s = csr[beg + i];
        float w = dinv[s];
        unsigned v = *(const unsigned*)(hnb + (size_t)s * D + col);
        ax = fmaf(w, __uint_as_float(v << 16), ax);
        ay = fmaf(w, __uint_as_float(v & 0xffff0000u), ay);
    }
    float dn = dinv[n];
    float dn2 = dn * dn;
    unsigned hv = *(const unsigned*)(hnb + (size_t)n * D + col);
    float2 bv = *(const float2*)&bias[col];
    float ox = fmaf(dn, ax, fmaf(dn2, __uint_as_float(hv << 16), bv.x));
    float oy = fmaf(dn, ay, fmaf(dn2, __uint_as_float(hv & 0xffff0000u), bv.y));
    float2 o = {ox, oy};
    *(float2*)&out[(size_t)n * D + col] = o;
}

extern "C" void kernel_launch(void* const* d_in, const int* in_sizes, int n_in,
                              void* d_out, int out_size, void* d_ws, size_t ws_size,
                              hipStream_t stream) {
    const float* x  = (const float*)d_in[0];
    const int*   ei = (const int*)d_in[1];
    const float* W1 = (const float*)d_in[2];
    const float* b1 = (const float*)d_in[3];
    const float* W2 = (const float*)d_in[4];
    const float* b2 = (const float*)d_in[5];
    float* out = (float*)d_out;

    const int* src = ei;
    const int* dst = ei + N_EDGES;

    // workspace layout (int units unless noted)
    int* wsi = (int*)d_ws;
    int*      cnt   = wsi;                        // [50176]
    int*      offs  = cnt + 50176;                // [50176]
    float*    dinv  = (float*)(offs + 50176);     // [50176]
    int*      bbase = (int*)(dinv + 50176);       // [256]
    int*      bsize = bbase + 256;                // [256]
    int*      H     = bsize + 256;                // [HB*NBUK = 25088]
    int*      B     = H + 25088;                  // [25088]
    unsigned* stage = (unsigned*)(B + 25088);     // [800000]
    int*      csr   = (int*)(stage + 800000);     // [800000]
    unsigned short* Wt = (unsigned short*)(csr + 800000);   // [2*32768]
    unsigned short* hn = Wt + 65536;                        // [N*128] bf16
    float* agg1 = (float*)(hn + (size_t)N_NODES * D + 64);  // [N*128] f32

    const int Bt = 256;
    const int gemm_grid = (N_NODES + 63) / 64;    // 782
    const int gather_grid = (N_NODES + 3) / 4;

    // prepw (blocks 0..127) + bucket histogram (blocks 128..255)
    prep_hist_kernel<<<256, Bt, 0, stream>>>(W1, W2, Wt, dst, H);
    kscan_kernel<<<1, Bt, 0, stream>>>(H, B, bbase, bsize);
    kstage_kernel<<<HB, Bt, 0, stream>>>(src, dst, B, stage);

    // gemm1 (blocks 0..781: hn = bf16(x @ W1)) + kfinal (blocks 782..977: CSR+dinv)
    gemm1_final_kernel<<<gemm_grid + NBUK, Bt, 0, stream>>>(
        x, Wt, hn, N_NODES, gemm_grid,
        stage, bbase, bsize, cnt, offs, dinv, csr);

    gather_kernel<<<gather_grid, Bt, 0, stream>>>(hn, dinv, offs, cnt, csr, b1, agg1);

    // layer 2: hn = bf16(relu(agg1) @ W2)
    mfma_gemm_relu_kernel<<<gemm_grid, Bt, 0, stream>>>(agg1, Wt + 32768, hn, N_NODES);
    gather_kernel<<<gather_grid, Bt, 0, stream>>>(hn, dinv, offs, cnt, csr, b2, out);
}